// Round 14
// baseline (298.862 us; speedup 1.0000x reference)
//
#include <hip/hip_runtime.h>
#include <stdint.h>
#include <limits.h>

// Problem constants (reference: B=4, N=8192, C=64, OUT=64, KNN=36)
#define BB 4
#define NN 8192
#define CC 64
#define OUTD 64
#define KK 36
#define NPTS (BB * NN)          // 32768
#define NBIN 129                // bins 0..128 (0 and 128 are clamp catch-alls)
// t = signed(float_bits(d2)) >> 20 (arith); bin = med3_i32(t,960,1088) - 960.
// Negative d2 (fp rounding) -> t very negative -> bin 0. One integer t per bin.

typedef float v2f __attribute__((ext_vector_type(2)));

static __device__ __forceinline__ int laneid() { return threadIdx.x & 63; }
static __device__ __forceinline__ int waveid_uniform() {
    return __builtin_amdgcn_readfirstlane((int)(threadIdx.x >> 6));
}
static __device__ __forceinline__ float rdlane_f(float v, int l) {
    return __int_as_float(__builtin_amdgcn_readlane(__float_as_int(v), l));
}
// DPP helper: VALU-pipe cross-lane (no LDS). ctrl/bound must be constants.
#define DPP_F(oldv, v, ctrl, bound) \
    __int_as_float(__builtin_amdgcn_update_dpp( \
        __float_as_int(oldv), __float_as_int(v), (ctrl), 0xf, 0xf, (bound)))

// 64-lane sum: result in lane 63 (row_shr prefix + row_bcast combine)
static __device__ __forceinline__ float wave_sum_dpp(float v) {
    v += DPP_F(0.0f, v, 0x111, true);   // row_shr:1
    v += DPP_F(0.0f, v, 0x112, true);   // row_shr:2
    v += DPP_F(0.0f, v, 0x114, true);   // row_shr:4
    v += DPP_F(0.0f, v, 0x118, true);   // row_shr:8
    v += DPP_F(0.0f, v, 0x142, true);   // row_bcast:15
    v += DPP_F(0.0f, v, 0x143, true);   // row_bcast:31
    return rdlane_f(v, 63);
}
// 64-lane max: OOB lanes keep old=v (no-op under max)
static __device__ __forceinline__ float wave_max_dpp(float v) {
    v = fmaxf(v, DPP_F(v, v, 0x111, false));
    v = fmaxf(v, DPP_F(v, v, 0x112, false));
    v = fmaxf(v, DPP_F(v, v, 0x114, false));
    v = fmaxf(v, DPP_F(v, v, 0x118, false));
    v = fmaxf(v, DPP_F(v, v, 0x142, false));
    v = fmaxf(v, DPP_F(v, v, 0x143, false));
    return rdlane_f(v, 63);
}

// ---------------------------------------------------------------------------
// Kernel 1: v_feat = relu([feature, xyz] @ W_v + b_v)  and pack xyzw.
// LDS-FREE: F rows and xyz are wave-uniform -> scalar-pipe s_load batches;
// the fma uses the SGPR as its single scalar operand. One wave = 8 points.
// Block = 256 = 4 waves = 32 points. grid = NPTS/32 = 1024 blocks.
// ---------------------------------------------------------------------------
__global__ __launch_bounds__(256) void k_vfeat(
    const float* __restrict__ feat, const float* __restrict__ xyz,
    const float* __restrict__ Wv, const float* __restrict__ bv,
    float* __restrict__ vfeat, float4* __restrict__ xyzw)
{
    const int lane = laneid();
    const int wv = waveid_uniform();
    const int pbase = blockIdx.x * 32 + wv * 8;

    const float b0 = bv[lane];
    float acc[8];
    #pragma unroll
    for (int pp = 0; pp < 8; ++pp) acc[pp] = b0;

    #pragma unroll 4
    for (int c = 0; c < CC; ++c) {
        const float w = Wv[c * OUTD + lane];
        #pragma unroll
        for (int pp = 0; pp < 8; ++pp)
            acc[pp] = fmaf(feat[(size_t)(pbase + pp) * CC + c], w, acc[pp]);
    }
    const float wx = Wv[64 * OUTD + lane];
    const float wy = Wv[65 * OUTD + lane];
    const float wz = Wv[66 * OUTD + lane];
    #pragma unroll
    for (int pp = 0; pp < 8; ++pp) {
        const float x = xyz[(pbase + pp) * 3 + 0];   // uniform -> s_load
        const float y = xyz[(pbase + pp) * 3 + 1];
        const float z = xyz[(pbase + pp) * 3 + 2];
        float a = acc[pp];
        a = fmaf(x, wx, a);
        a = fmaf(y, wy, a);
        a = fmaf(z, wz, a);
        vfeat[(size_t)(pbase + pp) * OUTD + lane] = fmaxf(a, 0.0f);
    }
    if (lane < 8) {
        const float x = xyz[(pbase + lane) * 3 + 0];
        const float y = xyz[(pbase + lane) * 3 + 1];
        const float z = xyz[(pbase + lane) * 3 + 2];
        xyzw[pbase + lane] = make_float4(x, y, z, (x * x + y * y) + z * z);
    }
}

// ---------------------------------------------------------------------------
// Kernel 2: 36-NN via per-query float-bit histogram selection. (R7 structure —
// best measured: 186 us; VALU + DS-atomics co-bound. Keep SGPR <= 64.)
// 512 blocks x 1024 thr, 64 queries/block = lane-per-query, 2 blocks/CU;
// packed candidate pairs (v_pk_fma_f32), AoS float4 via wave-uniform s_load.
// Histogram hist[bin][lane]: bank = lane%32, conflict-free 32-bit counts.
// Tie-break matches lax.top_k: (distance-bits, then smaller index).
// ---------------------------------------------------------------------------
__global__ __launch_bounds__(1024) void k_knn(
    const float4* __restrict__ xyzw, int* __restrict__ idx_ws)
{
    __shared__ __align__(16) uint32_t hist[NBIN * 64];  // 33 KB; reused as buf in pass 2
    __shared__ int binB[64];
    __shared__ int cumLoA[64];
    __shared__ uint32_t bufCnt[64];
    __shared__ uint32_t dirCnt[64];

    const int lane = laneid();
    const int wv = waveid_uniform();               // 0..15
    const int batch = blockIdx.x >> 7;             // 128 blocks per batch
    const int qbase = (blockIdx.x & 127) << 6;
    const int q = qbase + lane;                    // local query id 0..8191
    const float4* __restrict__ xw = xyzw + batch * NN;

    const float4 Q = xw[q];
    const v2f qx = { Q.x, Q.x };
    const v2f qy = { Q.y, Q.y };
    const v2f qz = { Q.z, Q.z };
    const v2f qw = { Q.w, Q.w };
    const v2f m2 = { -2.0f, -2.0f };

    const int j0 = wv * 512;
    const int laneAdj = lane - 960 * 64;           // fold bin rebase into addressing

    for (int i = threadIdx.x; i < NBIN * 64; i += 1024) hist[i] = 0u;
    if (threadIdx.x < 64) { bufCnt[threadIdx.x] = 0u; dirCnt[threadIdx.x] = 0u; }
    __syncthreads();

    // ---- pass 1: histogram of distance bits (2 candidates / iteration) ----
    #pragma unroll 4
    for (int j = j0; j < j0 + 512; j += 2) {
        float4 C0 = xw[j];                         // merged s_load_dwordx8
        float4 C1 = xw[j + 1];
        v2f cx = { C0.x, C1.x }, cy = { C0.y, C1.y };
        v2f cz = { C0.z, C1.z }, cw = { C0.w, C1.w };
        v2f dot = __builtin_elementwise_fma(qx, cx,
                  __builtin_elementwise_fma(qy, cy, qz * cz));
        v2f d2  = __builtin_elementwise_fma(m2, dot, qw + cw);
        int t0 = ((int)__float_as_uint(d2.x)) >> 20;   // arith shift: neg d -> very neg
        int t1 = ((int)__float_as_uint(d2.y)) >> 20;
        int m30 = min(max(t0, 960), 1088);             // v_med3_i32
        int m31 = min(max(t1, 960), 1088);
        atomicAdd(&hist[m30 * 64 + laneAdj], 1u);      // == hist[bin*64 + lane]
        atomicAdd(&hist[m31 * 64 + laneAdj], 1u);
    }
    __syncthreads();

    // ---- find crossing bin (threads 0..63, one query each) ----
    if (threadIdx.x < 64) {
        int cum = 0, Bq = 128, cl = 0;
        for (int b2 = 0; b2 < NBIN; ++b2) {
            int c = (int)hist[b2 * 64 + threadIdx.x];
            if (cum + c >= KK) { Bq = b2; cl = cum; break; }
            cum += c;
        }
        binB[threadIdx.x] = Bq;
        cumLoA[threadIdx.x] = cl;
    }
    __syncthreads();

    // ---- per-lane integer thresholds for pass 2 ----
    // direct (bin < Bq)    <=>  t <  TL
    // boundary (bin == Bq) <=>  !direct && t <= TH
    const int Bq = binB[lane];
    const int TL = (Bq > 0)    ? (960 + Bq) : INT_MIN;
    const int TH = (Bq == 128) ? INT_MAX    : (960 + Bq);
    const int grow = batch * NN + q;

    // buf[pos][lane] (transposed): 64 pos x 64 lanes x 8B = 32 KB (inside hist)
    unsigned long long* buf = (unsigned long long*)hist;

    // ---- pass 2: direct-emit strict members; buffer boundary-bin members ----
    #pragma unroll 4
    for (int j = j0; j < j0 + 512; j += 2) {
        float4 C0 = xw[j];
        float4 C1 = xw[j + 1];
        v2f cx = { C0.x, C1.x }, cy = { C0.y, C1.y };
        v2f cz = { C0.z, C1.z }, cw = { C0.w, C1.w };
        v2f dot = __builtin_elementwise_fma(qx, cx,
                  __builtin_elementwise_fma(qy, cy, qz * cz));
        v2f d2  = __builtin_elementwise_fma(m2, dot, qw + cw);
        int t0 = ((int)__float_as_uint(d2.x)) >> 20;
        int t1 = ((int)__float_as_uint(d2.y)) >> 20;
        if (t0 < TL) {
            uint32_t pos = atomicAdd(&dirCnt[lane], 1u);
            idx_ws[grow * KK + (int)pos] = batch * NN + j;
        } else if (t0 <= TH) {
            uint32_t db = __float_as_uint(fmaxf(d2.x, 0.0f));   // exact monotone key
            uint32_t pos = atomicAdd(&bufCnt[lane], 1u);
            if (pos < 64u) buf[(int)pos * 64 + lane] =
                ((unsigned long long)db << 32) | (uint32_t)j;
        }
        if (t1 < TL) {
            uint32_t pos = atomicAdd(&dirCnt[lane], 1u);
            idx_ws[grow * KK + (int)pos] = batch * NN + (j + 1);
        } else if (t1 <= TH) {
            uint32_t db = __float_as_uint(fmaxf(d2.y, 0.0f));
            uint32_t pos = atomicAdd(&bufCnt[lane], 1u);
            if (pos < 64u) buf[(int)pos * 64 + lane] =
                ((unsigned long long)db << 32) | (uint32_t)(j + 1);
        }
    }
    __syncthreads();

    // ---- final: pick (36 - cumLo) smallest exact keys from boundary bin ----
    if (threadIdx.x < 64) {
        const int t = threadIdx.x;
        const int q2 = qbase + t;
        const int grow2 = batch * NN + q2;
        const int cl = cumLoA[t];
        const int r = KK - cl;
        const int M = min((int)bufCnt[t], 64);
        const int outp = grow2 * KK + cl;
        for (int i = 0; i < r; ++i) {
            unsigned long long best = ~0ULL; int bi = -1;
            for (int u = 0; u < M; ++u) {
                unsigned long long v = buf[u * 64 + t];
                if (v < best) { best = v; bi = u; }
            }
            int jj;
            if (bi >= 0) { buf[bi * 64 + t] = ~0ULL; jj = (int)(best & 0xFFFFFFFFu); }
            else jj = q2;                            // pathological fallback
            if (jj < 0 || jj >= NN) jj = q2;
            idx_ws[outp + i] = batch * NN + jj;
        }
    }
}

// ---------------------------------------------------------------------------
// Kernel 3: attention + projection. LDS only for G staging, now stride 36
// (row = 144 B, 16B-aligned) so the logit phase reads each lane's row as
// 8 x ds_read_b128 (float4): per-phase banks (4*lane + c) cover all 32 ->
// conflict-free. LDS ops/point: 36 b32 writes + 16 b128 reads (was 164 b32).
// F from SGPRs; softmax via DPP; weights/projection via v_readlane.
// grid = NPTS/4 blocks of 256, one point per wave. ~20.7 KB LDS -> 7 blk/CU.
// ---------------------------------------------------------------------------
#define IDX(k) ((((k) & 3) == 0 ? I[(k) >> 2].x : ((k) & 3) == 1 ? I[(k) >> 2].y : \
                 ((k) & 3) == 2 ? I[(k) >> 2].z : I[(k) >> 2].w) & (NPTS - 1))

__global__ __launch_bounds__(256) void k_att(
    const float* __restrict__ feat, const float* __restrict__ vfeat,
    const int* __restrict__ idxw, const float* __restrict__ Wsuf,
    const float* __restrict__ bsuf, float* __restrict__ out)
{
    __shared__ __align__(16) float G[4][KK][36];   // 20,736 B
    const int lane = laneid();
    const int wv = waveid_uniform();
    const int p = blockIdx.x * 4 + wv;

    // preload all 36 neighbor indices (wave-uniform s_load)
    const int4* __restrict__ myidx4 = (const int4*)(idxw + p * KK);
    int4 I[9];
    #pragma unroll
    for (int t = 0; t < 9; ++t) I[t] = myidx4[t];

    const float* __restrict__ Fp = feat + (size_t)p * CC;  // uniform -> s_load

    const int half = lane >> 5;       // 0: rows 2kk, 1: rows 2kk+1
    const int cpart = lane & 31;      // column within the 32-wide half

    float a = 0.0f;
    #pragma unroll
    for (int h = 0; h < 2; ++h) {
        // stage half h: 18 wave-loads, each covering two rows' 32-col halves
        #pragma unroll
        for (int kk = 0; kk < 18; ++kk) {
            int jrow = half ? IDX(2 * kk + 1) : IDX(2 * kk);
            G[wv][2 * kk + half][cpart] = feat[(size_t)jrow * CC + h * 32 + cpart];
        }
        // partial logits over this channel half (lane = k < 36); F is scalar.
        // Row base lane*144 B and offsets 16B-multiples -> legal ds_read_b128.
        if (lane < KK) {
            const float4* __restrict__ Grow = (const float4*)(&G[wv][lane][0]);
            #pragma unroll
            for (int cc = 0; cc < 8; ++cc) {
                float4 g = Grow[cc];
                a = fmaf(Fp[h * 32 + 4 * cc + 0], g.x, a);
                a = fmaf(Fp[h * 32 + 4 * cc + 1], g.y, a);
                a = fmaf(Fp[h * 32 + 4 * cc + 2], g.z, a);
                a = fmaf(Fp[h * 32 + 4 * cc + 3], g.w, a);
            }
        }
    }
    const float logit = (lane < KK) ? a : -1e30f;

    // softmax across the 36 logit lanes — DPP (VALU pipe), no LDS
    const float m = wave_max_dpp(logit);
    const float e = (lane < KK) ? __expf(logit - m) : 0.0f;
    const float s = wave_sum_dpp(e);
    const float w = e * __frcp_rn(s);            // per-lane weight (0 for >=36)

    // weighted V gather: lane = channel; weight broadcast via v_readlane
    float acc = 0.0f;
    #pragma unroll
    for (int k = 0; k < KK; ++k) {
        float wk = rdlane_f(w, k);
        int j = IDX(k);
        acc = fmaf(wk, vfeat[j * OUTD + lane], acc);
    }

    // projection: o[lane] = b[lane] + sum_c acc_c * Wsuf[c][lane]
    // acc_c broadcast via v_readlane (VALU), Wsuf coalesced L1-hot
    float o = bsuf[lane];
    #pragma unroll 8
    for (int c = 0; c < OUTD; ++c) {
        float ac = rdlane_f(acc, c);
        o = fmaf(ac, Wsuf[c * OUTD + lane], o);
    }
    out[(size_t)p * OUTD + lane] = o;

    if (p == 0 && lane == 0) out[(size_t)NPTS * OUTD] = (float)NN;  // scalar N
}

// ---------------------------------------------------------------------------
extern "C" void kernel_launch(void* const* d_in, const int* in_sizes, int n_in,
                              void* d_out, int out_size, void* d_ws, size_t ws_size,
                              hipStream_t stream)
{
    const float* feat = (const float*)d_in[0];
    const float* xyz  = (const float*)d_in[1];
    const float* Wv   = (const float*)d_in[2];
    const float* bv   = (const float*)d_in[3];
    const float* Wsuf = (const float*)d_in[4];
    const float* bsuf = (const float*)d_in[5];
    float* out = (float*)d_out;

    char* ws = (char*)d_ws;
    float4* xyzw = (float4*)ws;                               // 512 KB
    float*  vfeat = (float*)(ws + (512 << 10));               // 8 MB
    int*    idxw  = (int*)(ws + (512 << 10) + (8 << 20));     // 4.5 MB

    k_vfeat<<<NPTS / 32, 256, 0, stream>>>(feat, xyz, Wv, bv, vfeat, xyzw);
    k_knn  <<<NPTS / 64, 1024, 0, stream>>>(xyzw, idxw);
    k_att  <<<NPTS / 4, 256, 0, stream>>>(feat, vfeat, idxw, Wsuf, bsuf, out);
}

// Round 15
// 276.620 us; speedup vs baseline: 1.0804x; 1.0804x over previous
//
#include <hip/hip_runtime.h>
#include <stdint.h>
#include <limits.h>

// Problem constants (reference: B=4, N=8192, C=64, OUT=64, KNN=36)
#define BB 4
#define NN 8192
#define CC 64
#define OUTD 64
#define KK 36
#define NPTS (BB * NN)          // 32768
#define NBIN 129                // bins 0..128 (0 and 128 are clamp catch-alls)
// t = signed(float_bits(d2)) >> 20 (arith); bin = med3_i32(t,960,1088) - 960.
// Negative d2 (fp rounding) -> t very negative -> bin 0. One integer t per bin.
//
// xyzw layout: PAIR-INTERLEAVED. For even j: 8 floats
//   [x_j, x_j1, y_j, y_j1, z_j, z_j1, w_j, w_j1]   (j1 = j+1; 32 B per pair)
// -> one wave-uniform s_load_dwordx8 per candidate pair, and each component
//    pair is an adjacent even-aligned SGPR pair = direct v_pk_fma_f32 operand
//    (zero packing v_movs, unlike AoS float4).

typedef float v2f __attribute__((ext_vector_type(2)));

static __device__ __forceinline__ int laneid() { return threadIdx.x & 63; }
static __device__ __forceinline__ int waveid_uniform() {
    return __builtin_amdgcn_readfirstlane((int)(threadIdx.x >> 6));
}
static __device__ __forceinline__ float rdlane_f(float v, int l) {
    return __int_as_float(__builtin_amdgcn_readlane(__float_as_int(v), l));
}
// DPP helper: VALU-pipe cross-lane (no LDS). ctrl/bound must be constants.
#define DPP_F(oldv, v, ctrl, bound) \
    __int_as_float(__builtin_amdgcn_update_dpp( \
        __float_as_int(oldv), __float_as_int(v), (ctrl), 0xf, 0xf, (bound)))

// 64-lane sum: result in lane 63 (row_shr prefix + row_bcast combine)
static __device__ __forceinline__ float wave_sum_dpp(float v) {
    v += DPP_F(0.0f, v, 0x111, true);   // row_shr:1
    v += DPP_F(0.0f, v, 0x112, true);   // row_shr:2
    v += DPP_F(0.0f, v, 0x114, true);   // row_shr:4
    v += DPP_F(0.0f, v, 0x118, true);   // row_shr:8
    v += DPP_F(0.0f, v, 0x142, true);   // row_bcast:15
    v += DPP_F(0.0f, v, 0x143, true);   // row_bcast:31
    return rdlane_f(v, 63);
}
// 64-lane max: OOB lanes keep old=v (no-op under max)
static __device__ __forceinline__ float wave_max_dpp(float v) {
    v = fmaxf(v, DPP_F(v, v, 0x111, false));
    v = fmaxf(v, DPP_F(v, v, 0x112, false));
    v = fmaxf(v, DPP_F(v, v, 0x114, false));
    v = fmaxf(v, DPP_F(v, v, 0x118, false));
    v = fmaxf(v, DPP_F(v, v, 0x142, false));
    v = fmaxf(v, DPP_F(v, v, 0x143, false));
    return rdlane_f(v, 63);
}

// ---------------------------------------------------------------------------
// Kernel 1: v_feat = relu([feature, xyz] @ W_v + b_v)  + pair-interleaved xyzw.
// (R13 structure — LDS staging for F rows; best measured total.)
// One wave handles 8 points. Block = 256 = 4 waves. grid = NPTS/32.
// ---------------------------------------------------------------------------
__global__ __launch_bounds__(256) void k_vfeat(
    const float* __restrict__ feat, const float* __restrict__ xyz,
    const float* __restrict__ Wv, const float* __restrict__ bv,
    float* __restrict__ vfeat, float* __restrict__ xp)   // xp: interleaved xyzw
{
    __shared__ float fb[4][8][64];
    __shared__ float xb[4][8][3];
    const int lane = laneid();
    const int wv = waveid_uniform();
    const int pbase = blockIdx.x * 32 + wv * 8;

    #pragma unroll
    for (int pp = 0; pp < 8; ++pp)
        fb[wv][pp][lane] = feat[(pbase + pp) * CC + lane];
    if (lane < 24)
        xb[wv][lane / 3][lane % 3] = xyz[pbase * 3 + lane];
    // same-wave LDS write->read: in-order per wave, compiler inserts lgkmcnt

    const float b0 = bv[lane];
    float acc[8];
    #pragma unroll
    for (int pp = 0; pp < 8; ++pp) acc[pp] = b0;

    #pragma unroll 4
    for (int c = 0; c < CC; ++c) {
        float w = Wv[c * OUTD + lane];
        #pragma unroll
        for (int pp = 0; pp < 8; ++pp)
            acc[pp] = fmaf(fb[wv][pp][c], w, acc[pp]);
    }
    const float wx = Wv[64 * OUTD + lane];
    const float wy = Wv[65 * OUTD + lane];
    const float wz = Wv[66 * OUTD + lane];
    #pragma unroll
    for (int pp = 0; pp < 8; ++pp) {
        float a = acc[pp];
        a = fmaf(xb[wv][pp][0], wx, a);
        a = fmaf(xb[wv][pp][1], wy, a);
        a = fmaf(xb[wv][pp][2], wz, a);
        vfeat[(pbase + pp) * OUTD + lane] = fmaxf(a, 0.0f);
    }
    if (lane < 8) {
        const int p = pbase + lane;
        const float x = xb[wv][lane][0], y = xb[wv][lane][1], z = xb[wv][lane][2];
        const float sq = (x * x + y * y) + z * z;
        const int base = (p >> 1) * 8 + (p & 1);    // pair-interleaved slot
        xp[base + 0] = x;
        xp[base + 2] = y;
        xp[base + 4] = z;
        xp[base + 6] = sq;
    }
}

// ---------------------------------------------------------------------------
// Kernel 2: 36-NN via per-query float-bit histogram selection.
// R7 partitioning (512 blocks x 1024 thr, 64 queries/block = lane-per-query,
// 2 blocks/CU = 32 waves/CU); candidates from the PAIR-INTERLEAVED layout:
// 4 consecutive wave-uniform v2f loads merge into one s_load_dwordx8 whose
// SGPR pairs feed v_pk_fma_f32 directly -> ~13 VALU / 2 candidates (was ~25
// with AoS float4: compiler spent ~8 v_movs packing {C0.x,C1.x} operands).
// Histogram hist[bin][lane]: bank = lane%32, conflict-free 32-bit counts.
// Tie-break matches lax.top_k: (distance-bits, then smaller index).
// ---------------------------------------------------------------------------
__global__ __launch_bounds__(1024) void k_knn(
    const float* __restrict__ xpAll, int* __restrict__ idx_ws)
{
    __shared__ __align__(16) uint32_t hist[NBIN * 64];  // 33 KB; reused as buf in pass 2
    __shared__ int binB[64];
    __shared__ int cumLoA[64];
    __shared__ uint32_t bufCnt[64];
    __shared__ uint32_t dirCnt[64];

    const int lane = laneid();
    const int wv = waveid_uniform();               // 0..15
    const int batch = blockIdx.x >> 7;             // 128 blocks per batch
    const int qbase = (blockIdx.x & 127) << 6;
    const int q = qbase + lane;                    // local query id 0..8191
    const float* __restrict__ xp = xpAll + (size_t)batch * NN * 4;
    const v2f* __restrict__ X2 = (const v2f*)xp;   // pair h -> X2[4h..4h+3]

    // per-lane query fetch from the interleaved layout (once per block)
    const int pr = q >> 1, sub = q & 1;
    const float Qx = xp[pr * 8 + sub + 0];
    const float Qy = xp[pr * 8 + sub + 2];
    const float Qz = xp[pr * 8 + sub + 4];
    const float Qw = xp[pr * 8 + sub + 6];
    const v2f qx = { Qx, Qx };
    const v2f qy = { Qy, Qy };
    const v2f qz = { Qz, Qz };
    const v2f qw = { Qw, Qw };
    const v2f m2 = { -2.0f, -2.0f };

    const int h0 = wv * 256;                       // pair-index base (512 cands)
    const int laneAdj = lane - 960 * 64;           // fold bin rebase into addressing

    for (int i = threadIdx.x; i < NBIN * 64; i += 1024) hist[i] = 0u;
    if (threadIdx.x < 64) { bufCnt[threadIdx.x] = 0u; dirCnt[threadIdx.x] = 0u; }
    __syncthreads();

    // ---- pass 1: histogram of distance bits (2 candidates / iteration) ----
    #pragma unroll 4
    for (int h = h0; h < h0 + 256; ++h) {
        v2f cx = X2[4 * h + 0];                    // merged s_load_dwordx8;
        v2f cy = X2[4 * h + 1];                    // each v2f = adjacent even
        v2f cz = X2[4 * h + 2];                    // SGPR pair = VOP3P operand
        v2f cw = X2[4 * h + 3];
        v2f dot = __builtin_elementwise_fma(qx, cx,
                  __builtin_elementwise_fma(qy, cy, qz * cz));
        v2f d2  = __builtin_elementwise_fma(m2, dot, qw + cw);
        int t0 = ((int)__float_as_uint(d2.x)) >> 20;   // arith shift: neg d -> very neg
        int t1 = ((int)__float_as_uint(d2.y)) >> 20;
        int m30 = min(max(t0, 960), 1088);             // v_med3_i32
        int m31 = min(max(t1, 960), 1088);
        atomicAdd(&hist[m30 * 64 + laneAdj], 1u);      // == hist[bin*64 + lane]
        atomicAdd(&hist[m31 * 64 + laneAdj], 1u);
    }
    __syncthreads();

    // ---- find crossing bin (threads 0..63, one query each) ----
    if (threadIdx.x < 64) {
        int cum = 0, Bq = 128, cl = 0;
        for (int b2 = 0; b2 < NBIN; ++b2) {
            int c = (int)hist[b2 * 64 + threadIdx.x];
            if (cum + c >= KK) { Bq = b2; cl = cum; break; }
            cum += c;
        }
        binB[threadIdx.x] = Bq;
        cumLoA[threadIdx.x] = cl;
    }
    __syncthreads();

    // ---- per-lane integer thresholds for pass 2 ----
    // direct (bin < Bq)    <=>  t <  TL
    // boundary (bin == Bq) <=>  !direct && t <= TH
    const int Bq = binB[lane];
    const int TL = (Bq > 0)    ? (960 + Bq) : INT_MIN;
    const int TH = (Bq == 128) ? INT_MAX    : (960 + Bq);
    const int grow = batch * NN + q;

    // buf[pos][lane] (transposed): 64 pos x 64 lanes x 8B = 32 KB (inside hist)
    unsigned long long* buf = (unsigned long long*)hist;

    // ---- pass 2: direct-emit strict members; buffer boundary-bin members ----
    #pragma unroll 4
    for (int h = h0; h < h0 + 256; ++h) {
        v2f cx = X2[4 * h + 0];
        v2f cy = X2[4 * h + 1];
        v2f cz = X2[4 * h + 2];
        v2f cw = X2[4 * h + 3];
        v2f dot = __builtin_elementwise_fma(qx, cx,
                  __builtin_elementwise_fma(qy, cy, qz * cz));
        v2f d2  = __builtin_elementwise_fma(m2, dot, qw + cw);
        int t0 = ((int)__float_as_uint(d2.x)) >> 20;
        int t1 = ((int)__float_as_uint(d2.y)) >> 20;
        const int j = 2 * h;
        if (t0 < TL) {
            uint32_t pos = atomicAdd(&dirCnt[lane], 1u);
            idx_ws[grow * KK + (int)pos] = batch * NN + j;
        } else if (t0 <= TH) {
            uint32_t db = __float_as_uint(fmaxf(d2.x, 0.0f));   // exact monotone key
            uint32_t pos = atomicAdd(&bufCnt[lane], 1u);
            if (pos < 64u) buf[(int)pos * 64 + lane] =
                ((unsigned long long)db << 32) | (uint32_t)j;
        }
        if (t1 < TL) {
            uint32_t pos = atomicAdd(&dirCnt[lane], 1u);
            idx_ws[grow * KK + (int)pos] = batch * NN + (j + 1);
        } else if (t1 <= TH) {
            uint32_t db = __float_as_uint(fmaxf(d2.y, 0.0f));
            uint32_t pos = atomicAdd(&bufCnt[lane], 1u);
            if (pos < 64u) buf[(int)pos * 64 + lane] =
                ((unsigned long long)db << 32) | (uint32_t)(j + 1);
        }
    }
    __syncthreads();

    // ---- final: pick (36 - cumLo) smallest exact keys from boundary bin ----
    if (threadIdx.x < 64) {
        const int t = threadIdx.x;
        const int q2 = qbase + t;
        const int grow2 = batch * NN + q2;
        const int cl = cumLoA[t];
        const int r = KK - cl;
        const int M = min((int)bufCnt[t], 64);
        const int outp = grow2 * KK + cl;
        for (int i = 0; i < r; ++i) {
            unsigned long long best = ~0ULL; int bi = -1;
            for (int u = 0; u < M; ++u) {
                unsigned long long v = buf[u * 64 + t];
                if (v < best) { best = v; bi = u; }
            }
            int jj;
            if (bi >= 0) { buf[bi * 64 + t] = ~0ULL; jj = (int)(best & 0xFFFFFFFFu); }
            else jj = q2;                            // pathological fallback
            if (jj < 0 || jj >= NN) jj = q2;
            idx_ws[outp + i] = batch * NN + jj;
        }
    }
}

// ---------------------------------------------------------------------------
// Kernel 3: attention + projection (R13 form — best measured). LDS only for
// G staging, two half-channel rounds G[4][36][33] (~19 KB -> 8 blocks/CU).
// F from SGPRs; softmax via DPP (VALU); weights/projection via v_readlane.
// grid = NPTS/4 blocks of 256, one point per wave. No __syncthreads.
// ---------------------------------------------------------------------------
#define IDX(k) ((((k) & 3) == 0 ? I[(k) >> 2].x : ((k) & 3) == 1 ? I[(k) >> 2].y : \
                 ((k) & 3) == 2 ? I[(k) >> 2].z : I[(k) >> 2].w) & (NPTS - 1))

__global__ __launch_bounds__(256) void k_att(
    const float* __restrict__ feat, const float* __restrict__ vfeat,
    const int* __restrict__ idxw, const float* __restrict__ Wsuf,
    const float* __restrict__ bsuf, float* __restrict__ out)
{
    __shared__ float G[4][KK][33];   // 19,008 B (stride 33 == 1 mod 32: <=2-way)
    const int lane = laneid();
    const int wv = waveid_uniform();
    const int p = blockIdx.x * 4 + wv;

    // preload all 36 neighbor indices (wave-uniform s_load)
    const int4* __restrict__ myidx4 = (const int4*)(idxw + p * KK);
    int4 I[9];
    #pragma unroll
    for (int t = 0; t < 9; ++t) I[t] = myidx4[t];

    const float* __restrict__ Fp = feat + (size_t)p * CC;  // uniform -> s_load

    const int half = lane >> 5;       // 0: rows 2kk, 1: rows 2kk+1
    const int cpart = lane & 31;      // column within the 32-wide half

    float a = 0.0f;
    #pragma unroll
    for (int h = 0; h < 2; ++h) {
        // stage half h: 18 wave-loads, each covering two rows' 32-col halves
        #pragma unroll
        for (int kk = 0; kk < 18; ++kk) {
            int jrow = half ? IDX(2 * kk + 1) : IDX(2 * kk);
            G[wv][2 * kk + half][cpart] = feat[(size_t)jrow * CC + h * 32 + cpart];
        }
        // partial logits over this channel half (lane = k < 36); F is scalar
        if (lane < KK) {
            #pragma unroll 8
            for (int c = 0; c < 32; ++c)
                a = fmaf(Fp[h * 32 + c], G[wv][lane][c], a);
        }
    }
    const float logit = (lane < KK) ? a : -1e30f;

    // softmax across the 36 logit lanes — DPP (VALU pipe), no LDS
    const float m = wave_max_dpp(logit);
    const float e = (lane < KK) ? __expf(logit - m) : 0.0f;
    const float s = wave_sum_dpp(e);
    const float w = e * __frcp_rn(s);            // per-lane weight (0 for >=36)

    // weighted V gather: lane = channel; weight broadcast via v_readlane
    float acc = 0.0f;
    #pragma unroll
    for (int k = 0; k < KK; ++k) {
        float wk = rdlane_f(w, k);
        int j = IDX(k);
        acc = fmaf(wk, vfeat[j * OUTD + lane], acc);
    }

    // projection: o[lane] = b[lane] + sum_c acc_c * Wsuf[c][lane]
    float o = bsuf[lane];
    #pragma unroll 8
    for (int c = 0; c < OUTD; ++c) {
        float ac = rdlane_f(acc, c);
        o = fmaf(ac, Wsuf[c * OUTD + lane], o);
    }
    out[(size_t)p * OUTD + lane] = o;

    if (p == 0 && lane == 0) out[(size_t)NPTS * OUTD] = (float)NN;  // scalar N
}

// ---------------------------------------------------------------------------
extern "C" void kernel_launch(void* const* d_in, const int* in_sizes, int n_in,
                              void* d_out, int out_size, void* d_ws, size_t ws_size,
                              hipStream_t stream)
{
    const float* feat = (const float*)d_in[0];
    const float* xyz  = (const float*)d_in[1];
    const float* Wv   = (const float*)d_in[2];
    const float* bv   = (const float*)d_in[3];
    const float* Wsuf = (const float*)d_in[4];
    const float* bsuf = (const float*)d_in[5];
    float* out = (float*)d_out;

    char* ws = (char*)d_ws;
    float* xp = (float*)ws;                                   // 512 KB interleaved
    float*  vfeat = (float*)(ws + (512 << 10));               // 8 MB
    int*    idxw  = (int*)(ws + (512 << 10) + (8 << 20));     // 4.5 MB

    k_vfeat<<<NPTS / 32, 256, 0, stream>>>(feat, xyz, Wv, bv, vfeat, xp);
    k_knn  <<<NPTS / 64, 1024, 0, stream>>>(xp, idxw);
    k_att  <<<NPTS / 4, 256, 0, stream>>>(feat, vfeat, idxw, Wsuf, bsuf, out);
}

// Round 16
// 251.638 us; speedup vs baseline: 1.1877x; 1.0993x over previous
//
#include <hip/hip_runtime.h>
#include <stdint.h>
#include <limits.h>

// Problem constants (reference: B=4, N=8192, C=64, OUT=64, KNN=36)
#define BB 4
#define NN 8192
#define CC 64
#define OUTD 64
#define KK 36
#define NPTS (BB * NN)          // 32768
#define NBIN 129                // bins 0..128 (0 and 128 are clamp catch-alls)
// t = signed(float_bits(d2)) >> 20 (arith); bin = med3_i32(t,960,1088) - 960.
// Negative d2 (fp rounding) -> t very negative -> bin 0. One integer t per bin.
//
// xyzw layout: PAIR-INTERLEAVED. For even j: 8 floats
//   [x_j, x_j1, y_j, y_j1, z_j, z_j1, w_j, w_j1]   (j1 = j+1; 32 B per pair)
// -> wave-uniform s_load_dwordx8/x16 batches; each component pair is an
//    adjacent even-aligned SGPR pair = direct v_pk_fma_f32 operand.

typedef float v2f __attribute__((ext_vector_type(2)));

static __device__ __forceinline__ int laneid() { return threadIdx.x & 63; }
static __device__ __forceinline__ int waveid_uniform() {
    return __builtin_amdgcn_readfirstlane((int)(threadIdx.x >> 6));
}
static __device__ __forceinline__ float rdlane_f(float v, int l) {
    return __int_as_float(__builtin_amdgcn_readlane(__float_as_int(v), l));
}
// DPP helper: VALU-pipe cross-lane (no LDS). ctrl/bound must be constants.
#define DPP_F(oldv, v, ctrl, bound) \
    __int_as_float(__builtin_amdgcn_update_dpp( \
        __float_as_int(oldv), __float_as_int(v), (ctrl), 0xf, 0xf, (bound)))

// 64-lane sum: result in lane 63 (row_shr prefix + row_bcast combine)
static __device__ __forceinline__ float wave_sum_dpp(float v) {
    v += DPP_F(0.0f, v, 0x111, true);   // row_shr:1
    v += DPP_F(0.0f, v, 0x112, true);   // row_shr:2
    v += DPP_F(0.0f, v, 0x114, true);   // row_shr:4
    v += DPP_F(0.0f, v, 0x118, true);   // row_shr:8
    v += DPP_F(0.0f, v, 0x142, true);   // row_bcast:15
    v += DPP_F(0.0f, v, 0x143, true);   // row_bcast:31
    return rdlane_f(v, 63);
}
// 64-lane max: OOB lanes keep old=v (no-op under max)
static __device__ __forceinline__ float wave_max_dpp(float v) {
    v = fmaxf(v, DPP_F(v, v, 0x111, false));
    v = fmaxf(v, DPP_F(v, v, 0x112, false));
    v = fmaxf(v, DPP_F(v, v, 0x114, false));
    v = fmaxf(v, DPP_F(v, v, 0x118, false));
    v = fmaxf(v, DPP_F(v, v, 0x142, false));
    v = fmaxf(v, DPP_F(v, v, 0x143, false));
    return rdlane_f(v, 63);
}

// ---------------------------------------------------------------------------
// Kernel 1: v_feat = relu([feature, xyz] @ W_v + b_v)  + pair-interleaved xyzw.
// One wave handles 8 points. Block = 256 = 4 waves. grid = NPTS/32.
// ---------------------------------------------------------------------------
__global__ __launch_bounds__(256) void k_vfeat(
    const float* __restrict__ feat, const float* __restrict__ xyz,
    const float* __restrict__ Wv, const float* __restrict__ bv,
    float* __restrict__ vfeat, float* __restrict__ xp)   // xp: interleaved xyzw
{
    __shared__ float fb[4][8][64];
    __shared__ float xb[4][8][3];
    const int lane = laneid();
    const int wv = waveid_uniform();
    const int pbase = blockIdx.x * 32 + wv * 8;

    #pragma unroll
    for (int pp = 0; pp < 8; ++pp)
        fb[wv][pp][lane] = feat[(pbase + pp) * CC + lane];
    if (lane < 24)
        xb[wv][lane / 3][lane % 3] = xyz[pbase * 3 + lane];
    // same-wave LDS write->read: in-order per wave, compiler inserts lgkmcnt

    const float b0 = bv[lane];
    float acc[8];
    #pragma unroll
    for (int pp = 0; pp < 8; ++pp) acc[pp] = b0;

    #pragma unroll 4
    for (int c = 0; c < CC; ++c) {
        float w = Wv[c * OUTD + lane];
        #pragma unroll
        for (int pp = 0; pp < 8; ++pp)
            acc[pp] = fmaf(fb[wv][pp][c], w, acc[pp]);
    }
    const float wx = Wv[64 * OUTD + lane];
    const float wy = Wv[65 * OUTD + lane];
    const float wz = Wv[66 * OUTD + lane];
    #pragma unroll
    for (int pp = 0; pp < 8; ++pp) {
        float a = acc[pp];
        a = fmaf(xb[wv][pp][0], wx, a);
        a = fmaf(xb[wv][pp][1], wy, a);
        a = fmaf(xb[wv][pp][2], wz, a);
        vfeat[(pbase + pp) * OUTD + lane] = fmaxf(a, 0.0f);
    }
    if (lane < 8) {
        const int p = pbase + lane;
        const float x = xb[wv][lane][0], y = xb[wv][lane][1], z = xb[wv][lane][2];
        const float sq = (x * x + y * y) + z * z;
        const int base = (p >> 1) * 8 + (p & 1);    // pair-interleaved slot
        xp[base + 0] = x;
        xp[base + 2] = y;
        xp[base + 4] = z;
        xp[base + 6] = sq;
    }
}

// ---------------------------------------------------------------------------
// Kernel 2: 36-NN via per-query float-bit histogram selection.
// R7 partitioning (512 blocks x 1024 thr, 64 queries/block = lane-per-query,
// 2 blocks/CU = 32 waves/CU); PAIR-INTERLEAVED candidates; 4 candidates per
// iteration (2 pairs -> one s_load_dwordx16); v_pk_fma_f32 math.
// Pass 2 hot path = ONE compare (t <= TH); direct/boundary split inside the
// rarely-taken branch (TL == TH for interior bins).
// Histogram hist[bin][lane]: bank = lane%32, conflict-free 32-bit counts.
// Tie-break matches lax.top_k: (distance-bits, then smaller index).
// ---------------------------------------------------------------------------
__global__ __launch_bounds__(1024) void k_knn(
    const float* __restrict__ xpAll, int* __restrict__ idx_ws)
{
    __shared__ __align__(16) uint32_t hist[NBIN * 64];  // 33 KB; reused as buf in pass 2
    __shared__ int binB[64];
    __shared__ int cumLoA[64];
    __shared__ uint32_t bufCnt[64];
    __shared__ uint32_t dirCnt[64];

    const int lane = laneid();
    const int wv = waveid_uniform();               // 0..15
    const int batch = blockIdx.x >> 7;             // 128 blocks per batch
    const int qbase = (blockIdx.x & 127) << 6;
    const int q = qbase + lane;                    // local query id 0..8191
    const float* __restrict__ xp = xpAll + (size_t)batch * NN * 4;
    const v2f* __restrict__ X2 = (const v2f*)xp;   // pair h -> X2[4h..4h+3]

    // per-lane query fetch from the interleaved layout (once per block)
    const int pr = q >> 1, sub = q & 1;
    const float Qx = xp[pr * 8 + sub + 0];
    const float Qy = xp[pr * 8 + sub + 2];
    const float Qz = xp[pr * 8 + sub + 4];
    const float Qw = xp[pr * 8 + sub + 6];
    const v2f qx = { Qx, Qx };
    const v2f qy = { Qy, Qy };
    const v2f qz = { Qz, Qz };
    const v2f qw = { Qw, Qw };
    const v2f m2 = { -2.0f, -2.0f };

    const int h0 = wv * 256;                       // pair-index base (512 cands)
    const int laneAdj = lane - 960 * 64;           // fold bin rebase into addressing

    for (int i = threadIdx.x; i < NBIN * 64; i += 1024) hist[i] = 0u;
    if (threadIdx.x < 64) { bufCnt[threadIdx.x] = 0u; dirCnt[threadIdx.x] = 0u; }
    __syncthreads();

    // ---- pass 1: histogram of distance bits (4 candidates / iteration) ----
    #pragma unroll 2
    for (int h = h0; h < h0 + 256; h += 2) {
        v2f cx0 = X2[4 * h + 0];                   // 2 pairs -> s_load_dwordx16
        v2f cy0 = X2[4 * h + 1];
        v2f cz0 = X2[4 * h + 2];
        v2f cw0 = X2[4 * h + 3];
        v2f cx1 = X2[4 * h + 4];
        v2f cy1 = X2[4 * h + 5];
        v2f cz1 = X2[4 * h + 6];
        v2f cw1 = X2[4 * h + 7];
        v2f dot0 = __builtin_elementwise_fma(qx, cx0,
                   __builtin_elementwise_fma(qy, cy0, qz * cz0));
        v2f d20  = __builtin_elementwise_fma(m2, dot0, qw + cw0);
        v2f dot1 = __builtin_elementwise_fma(qx, cx1,
                   __builtin_elementwise_fma(qy, cy1, qz * cz1));
        v2f d21  = __builtin_elementwise_fma(m2, dot1, qw + cw1);
        int t0 = ((int)__float_as_uint(d20.x)) >> 20;  // arith: neg d -> very neg
        int t1 = ((int)__float_as_uint(d20.y)) >> 20;
        int t2 = ((int)__float_as_uint(d21.x)) >> 20;
        int t3 = ((int)__float_as_uint(d21.y)) >> 20;
        int m30 = min(max(t0, 960), 1088);             // v_med3_i32
        int m31 = min(max(t1, 960), 1088);
        int m32 = min(max(t2, 960), 1088);
        int m33 = min(max(t3, 960), 1088);
        atomicAdd(&hist[m30 * 64 + laneAdj], 1u);      // == hist[bin*64 + lane]
        atomicAdd(&hist[m31 * 64 + laneAdj], 1u);
        atomicAdd(&hist[m32 * 64 + laneAdj], 1u);
        atomicAdd(&hist[m33 * 64 + laneAdj], 1u);
    }
    __syncthreads();

    // ---- find crossing bin (threads 0..63, one query each) ----
    if (threadIdx.x < 64) {
        int cum = 0, Bq = 128, cl = 0;
        for (int b2 = 0; b2 < NBIN; ++b2) {
            int c = (int)hist[b2 * 64 + threadIdx.x];
            if (cum + c >= KK) { Bq = b2; cl = cum; break; }
            cum += c;
        }
        binB[threadIdx.x] = Bq;
        cumLoA[threadIdx.x] = cl;
    }
    __syncthreads();

    // ---- per-lane integer thresholds for pass 2 ----
    // relevant (bin <= Bq) <=> t <= TH;  within that: direct <=> t < TL
    const int Bq = binB[lane];
    const int TL = (Bq > 0)    ? (960 + Bq) : INT_MIN;
    const int TH = (Bq == 128) ? INT_MAX    : (960 + Bq);
    const int grow = batch * NN + q;

    // buf[pos][lane] (transposed): 64 pos x 64 lanes x 8B = 32 KB (inside hist)
    unsigned long long* buf = (unsigned long long*)hist;

    // ---- pass 2: one-compare hot path; rare exec-masked emit ----
    #pragma unroll 2
    for (int h = h0; h < h0 + 256; h += 2) {
        v2f cx0 = X2[4 * h + 0];
        v2f cy0 = X2[4 * h + 1];
        v2f cz0 = X2[4 * h + 2];
        v2f cw0 = X2[4 * h + 3];
        v2f cx1 = X2[4 * h + 4];
        v2f cy1 = X2[4 * h + 5];
        v2f cz1 = X2[4 * h + 6];
        v2f cw1 = X2[4 * h + 7];
        v2f dot0 = __builtin_elementwise_fma(qx, cx0,
                   __builtin_elementwise_fma(qy, cy0, qz * cz0));
        v2f d20  = __builtin_elementwise_fma(m2, dot0, qw + cw0);
        v2f dot1 = __builtin_elementwise_fma(qx, cx1,
                   __builtin_elementwise_fma(qy, cy1, qz * cz1));
        v2f d21  = __builtin_elementwise_fma(m2, dot1, qw + cw1);
        int t0 = ((int)__float_as_uint(d20.x)) >> 20;
        int t1 = ((int)__float_as_uint(d20.y)) >> 20;
        int t2 = ((int)__float_as_uint(d21.x)) >> 20;
        int t3 = ((int)__float_as_uint(d21.y)) >> 20;
        const int j = 2 * h;
        #pragma unroll
        for (int u = 0; u < 4; ++u) {
            const int tu = (u == 0) ? t0 : (u == 1) ? t1 : (u == 2) ? t2 : t3;
            if (tu <= TH) {                         // rare (~1% of candidates)
                const float du = (u == 0) ? d20.x : (u == 1) ? d20.y
                               : (u == 2) ? d21.x : d21.y;
                if (tu < TL) {
                    uint32_t pos = atomicAdd(&dirCnt[lane], 1u);
                    idx_ws[grow * KK + (int)pos] = batch * NN + (j + u);
                } else {
                    uint32_t db = __float_as_uint(fmaxf(du, 0.0f)); // exact key
                    uint32_t pos = atomicAdd(&bufCnt[lane], 1u);
                    if (pos < 64u) buf[(int)pos * 64 + lane] =
                        ((unsigned long long)db << 32) | (uint32_t)(j + u);
                }
            }
        }
    }
    __syncthreads();

    // ---- final: pick (36 - cumLo) smallest exact keys from boundary bin ----
    if (threadIdx.x < 64) {
        const int t = threadIdx.x;
        const int q2 = qbase + t;
        const int grow2 = batch * NN + q2;
        const int cl = cumLoA[t];
        const int r = KK - cl;
        const int M = min((int)bufCnt[t], 64);
        const int outp = grow2 * KK + cl;
        for (int i = 0; i < r; ++i) {
            unsigned long long best = ~0ULL; int bi = -1;
            for (int u = 0; u < M; ++u) {
                unsigned long long v = buf[u * 64 + t];
                if (v < best) { best = v; bi = u; }
            }
            int jj;
            if (bi >= 0) { buf[bi * 64 + t] = ~0ULL; jj = (int)(best & 0xFFFFFFFFu); }
            else jj = q2;                            // pathological fallback
            if (jj < 0 || jj >= NN) jj = q2;
            idx_ws[outp + i] = batch * NN + jj;
        }
    }
}

// ---------------------------------------------------------------------------
// Kernel 3: attention + projection (best-measured form). LDS only for
// G staging, two half-channel rounds G[4][36][33] (~19 KB -> 8 blocks/CU).
// F from SGPRs; softmax via DPP (VALU); weights/projection via v_readlane.
// grid = NPTS/4 blocks of 256, one point per wave. No __syncthreads.
// ---------------------------------------------------------------------------
#define IDX(k) ((((k) & 3) == 0 ? I[(k) >> 2].x : ((k) & 3) == 1 ? I[(k) >> 2].y : \
                 ((k) & 3) == 2 ? I[(k) >> 2].z : I[(k) >> 2].w) & (NPTS - 1))

__global__ __launch_bounds__(256) void k_att(
    const float* __restrict__ feat, const float* __restrict__ vfeat,
    const int* __restrict__ idxw, const float* __restrict__ Wsuf,
    const float* __restrict__ bsuf, float* __restrict__ out)
{
    __shared__ float G[4][KK][33];   // 19,008 B (stride 33 == 1 mod 32: <=2-way)
    const int lane = laneid();
    const int wv = waveid_uniform();
    const int p = blockIdx.x * 4 + wv;

    // preload all 36 neighbor indices (wave-uniform s_load)
    const int4* __restrict__ myidx4 = (const int4*)(idxw + p * KK);
    int4 I[9];
    #pragma unroll
    for (int t = 0; t < 9; ++t) I[t] = myidx4[t];

    const float* __restrict__ Fp = feat + (size_t)p * CC;  // uniform -> s_load

    const int half = lane >> 5;       // 0: rows 2kk, 1: rows 2kk+1
    const int cpart = lane & 31;      // column within the 32-wide half

    float a = 0.0f;
    #pragma unroll
    for (int h = 0; h < 2; ++h) {
        // stage half h: 18 wave-loads, each covering two rows' 32-col halves
        #pragma unroll
        for (int kk = 0; kk < 18; ++kk) {
            int jrow = half ? IDX(2 * kk + 1) : IDX(2 * kk);
            G[wv][2 * kk + half][cpart] = feat[(size_t)jrow * CC + h * 32 + cpart];
        }
        // partial logits over this channel half (lane = k < 36); F is scalar
        if (lane < KK) {
            #pragma unroll 8
            for (int c = 0; c < 32; ++c)
                a = fmaf(Fp[h * 32 + c], G[wv][lane][c], a);
        }
    }
    const float logit = (lane < KK) ? a : -1e30f;

    // softmax across the 36 logit lanes — DPP (VALU pipe), no LDS
    const float m = wave_max_dpp(logit);
    const float e = (lane < KK) ? __expf(logit - m) : 0.0f;
    const float s = wave_sum_dpp(e);
    const float w = e * __frcp_rn(s);            // per-lane weight (0 for >=36)

    // weighted V gather: lane = channel; weight broadcast via v_readlane
    float acc = 0.0f;
    #pragma unroll
    for (int k = 0; k < KK; ++k) {
        float wk = rdlane_f(w, k);
        int j = IDX(k);
        acc = fmaf(wk, vfeat[j * OUTD + lane], acc);
    }

    // projection: o[lane] = b[lane] + sum_c acc_c * Wsuf[c][lane]
    float o = bsuf[lane];
    #pragma unroll 8
    for (int c = 0; c < OUTD; ++c) {
        float ac = rdlane_f(acc, c);
        o = fmaf(ac, Wsuf[c * OUTD + lane], o);
    }
    out[(size_t)p * OUTD + lane] = o;

    if (p == 0 && lane == 0) out[(size_t)NPTS * OUTD] = (float)NN;  // scalar N
}

// ---------------------------------------------------------------------------
extern "C" void kernel_launch(void* const* d_in, const int* in_sizes, int n_in,
                              void* d_out, int out_size, void* d_ws, size_t ws_size,
                              hipStream_t stream)
{
    const float* feat = (const float*)d_in[0];
    const float* xyz  = (const float*)d_in[1];
    const float* Wv   = (const float*)d_in[2];
    const float* bv   = (const float*)d_in[3];
    const float* Wsuf = (const float*)d_in[4];
    const float* bsuf = (const float*)d_in[5];
    float* out = (float*)d_out;

    char* ws = (char*)d_ws;
    float* xp = (float*)ws;                                   // 512 KB interleaved
    float*  vfeat = (float*)(ws + (512 << 10));               // 8 MB
    int*    idxw  = (int*)(ws + (512 << 10) + (8 << 20));     // 4.5 MB

    k_vfeat<<<NPTS / 32, 256, 0, stream>>>(feat, xyz, Wv, bv, vfeat, xp);
    k_knn  <<<NPTS / 64, 1024, 0, stream>>>(xp, idxw);
    k_att  <<<NPTS / 4, 256, 0, stream>>>(feat, vfeat, idxw, Wsuf, bsuf, out);
}